// Round 1
// baseline (300.362 us; speedup 1.0000x reference)
//
#include <hip/hip_runtime.h>
#include <math.h>

// Problem constants (from reference: B=8, T=4096, D=1024, fp32)
#define BB 8
#define TT 4096
#define DD 1024
#define NC 64            // number of T-chunks
#define CT (TT / NC)     // chunk length = 64
#define D4 (DD / 4)      // float4s per row = 256

__device__ __forceinline__ float gelu_exact(float v) {
    // exact GELU: 0.5*v*(1+erf(v/sqrt(2)))
    return 0.5f * v * (1.0f + erff(v * 0.70710678118654752f));
}

// Pass 1: per-(b,chunk) masked sums of gelu(x) over the chunk's T range.
// ws layout: [B][NC][D] floats.
__global__ __launch_bounds__(256)
void k_partial(const float* __restrict__ x, const int* __restrict__ lengths,
               float* __restrict__ ws) {
    const int c  = blockIdx.x;       // chunk
    const int b  = blockIdx.y;       // batch
    const int d4 = threadIdx.x;      // 0..255 (float4 column)
    const int len = lengths[b];
    const int t0 = c * CT;
    const int t1 = min(t0 + CT, len);   // masked end (g==0 beyond len)

    const float4* __restrict__ xp = (const float4*)(x + (size_t)b * TT * DD);
    float4 s = make_float4(0.f, 0.f, 0.f, 0.f);
    #pragma unroll 4
    for (int t = t0; t < t1; ++t) {
        float4 v = xp[(size_t)t * D4 + d4];
        s.x += gelu_exact(v.x);
        s.y += gelu_exact(v.y);
        s.z += gelu_exact(v.z);
        s.w += gelu_exact(v.w);
    }
    ((float4*)ws)[((size_t)b * NC + c) * D4 + d4] = s;
}

// Pass 2: in-place exclusive scan of chunk sums along NC, per (b,d) column.
// grid: (DD/256, BB) blocks, 256 threads. Tiny (2 MB, L2-resident).
__global__ __launch_bounds__(256)
void k_scan(float* __restrict__ ws) {
    const int b = blockIdx.y;
    const int d = blockIdx.x * 256 + threadIdx.x;   // 0..1023
    float* p = ws + (size_t)b * NC * DD + d;
    float run = 0.f;
    #pragma unroll 8
    for (int c = 0; c < NC; ++c) {
        float v = p[(size_t)c * DD];
        p[(size_t)c * DD] = run;
        run += v;
    }
}

// Pass 3: re-read x, add exclusive chunk offset + local running prefix.
// out[b,t] = x[b,t] + (t<len ? prefix[b,t] : 0)
__global__ __launch_bounds__(256)
void k_apply(const float* __restrict__ x, const int* __restrict__ lengths,
             const float* __restrict__ ws, float* __restrict__ out) {
    const int c  = blockIdx.x;
    const int b  = blockIdx.y;
    const int d4 = threadIdx.x;
    const int len = lengths[b];
    const int t0 = c * CT;
    const int tv = min(t0 + CT, len);   // valid (masked-in) end

    const float4* __restrict__ xp = (const float4*)(x + (size_t)b * TT * DD);
    float4* __restrict__ op = (float4*)(out + (size_t)b * TT * DD);

    float4 pre = ((const float4*)ws)[((size_t)b * NC + c) * D4 + d4];

    int t = t0;
    #pragma unroll 4
    for (; t < tv; ++t) {
        float4 v = xp[(size_t)t * D4 + d4];
        pre.x += gelu_exact(v.x);
        pre.y += gelu_exact(v.y);
        pre.z += gelu_exact(v.z);
        pre.w += gelu_exact(v.w);
        float4 o;
        o.x = v.x + pre.x;
        o.y = v.y + pre.y;
        o.z = v.z + pre.z;
        o.w = v.w + pre.w;
        op[(size_t)t * D4 + d4] = o;
    }
    // rows at/after length: plain copy (mask is 0)
    #pragma unroll 4
    for (; t < t0 + CT; ++t) {
        op[(size_t)t * D4 + d4] = xp[(size_t)t * D4 + d4];
    }
}

extern "C" void kernel_launch(void* const* d_in, const int* in_sizes, int n_in,
                              void* d_out, int out_size, void* d_ws, size_t ws_size,
                              hipStream_t stream) {
    const float* x       = (const float*)d_in[0];
    const int*   lengths = (const int*)d_in[1];
    float*       out     = (float*)d_out;
    float*       ws      = (float*)d_ws;   // needs B*NC*D*4 = 2 MB

    dim3 blk(256, 1, 1);
    dim3 g1(NC, BB, 1);
    hipLaunchKernelGGL(k_partial, g1, blk, 0, stream, x, lengths, ws);

    dim3 g2(DD / 256, BB, 1);
    hipLaunchKernelGGL(k_scan, g2, blk, 0, stream, ws);

    hipLaunchKernelGGL(k_apply, g1, blk, 0, stream, x, lengths, ws, out);
}

// Round 2
// 287.043 us; speedup vs baseline: 1.0464x; 1.0464x over previous
//
#include <hip/hip_runtime.h>
#include <math.h>

// Problem constants (from reference: B=8, T=4096, D=1024, fp32)
#define BB 8
#define TT 4096
#define DD 1024
#define NC 256           // number of T-chunks
#define CT (TT / NC)     // chunk length = 16
#define D4 (DD / 4)      // float4s per row = 256
#define CPL (NC / 64)    // chunks per lane in wave scan = 4

__device__ __forceinline__ float gelu_exact(float v) {
    // exact GELU: 0.5*v*(1+erf(v/sqrt(2)))
    return 0.5f * v * (1.0f + erff(v * 0.70710678118654752f));
}

// Pass 1: per-(b,chunk) masked sums of gelu(x) over the chunk's T range.
// ws layout: [B][NC][D] floats (8 MB).
__global__ __launch_bounds__(256)
void k_partial(const float* __restrict__ x, const int* __restrict__ lengths,
               float* __restrict__ ws) {
    const int c  = blockIdx.x;       // chunk
    const int b  = blockIdx.y;       // batch
    const int d4 = threadIdx.x;      // 0..255 (float4 column)
    const int len = lengths[b];
    const int t0 = c * CT;
    const int t1 = min(t0 + CT, len);   // masked end (g==0 beyond len)

    const float4* __restrict__ xp = (const float4*)(x + (size_t)b * TT * DD);
    float4 s = make_float4(0.f, 0.f, 0.f, 0.f);
    #pragma unroll 4
    for (int t = t0; t < t1; ++t) {
        float4 v = xp[(size_t)t * D4 + d4];
        s.x += gelu_exact(v.x);
        s.y += gelu_exact(v.y);
        s.z += gelu_exact(v.z);
        s.w += gelu_exact(v.w);
    }
    ((float4*)ws)[((size_t)b * NC + c) * D4 + d4] = s;
}

// Pass 2: exclusive scan of the NC chunk sums, one 64-lane wave per (b,d)
// column, CPL=4 contiguous chunks per lane, __shfl_up wave scan.
// grid: B*DD/4 blocks of 256 threads (4 waves/block).
__global__ __launch_bounds__(256)
void k_scan(float* __restrict__ ws) {
    const int wave = threadIdx.x >> 6;            // 0..3
    const int lane = threadIdx.x & 63;
    const int col  = blockIdx.x * 4 + wave;       // 0 .. B*DD-1
    const int b = col >> 10;                      // / DD
    const int d = col & (DD - 1);                 // % DD

    float* p = ws + (size_t)b * NC * DD + d;
    const int c0 = lane * CPL;

    float v[CPL];
    #pragma unroll
    for (int k = 0; k < CPL; ++k) v[k] = p[(size_t)(c0 + k) * DD];

    // local inclusive totals
    float tot = 0.f;
    float loc[CPL];                               // exclusive-within-lane
    #pragma unroll
    for (int k = 0; k < CPL; ++k) { loc[k] = tot; tot += v[k]; }

    // wave inclusive scan of tot
    float inc = tot;
    #pragma unroll
    for (int off = 1; off < 64; off <<= 1) {
        float n = __shfl_up(inc, off, 64);
        if (lane >= off) inc += n;
    }
    const float excl = inc - tot;                 // sum of all previous lanes

    #pragma unroll
    for (int k = 0; k < CPL; ++k) p[(size_t)(c0 + k) * DD] = excl + loc[k];
}

// Pass 3: re-read x, add exclusive chunk offset + local running prefix.
__global__ __launch_bounds__(256)
void k_apply(const float* __restrict__ x, const int* __restrict__ lengths,
             const float* __restrict__ ws, float* __restrict__ out) {
    const int c  = blockIdx.x;
    const int b  = blockIdx.y;
    const int d4 = threadIdx.x;
    const int len = lengths[b];
    const int t0 = c * CT;
    const int tv = min(t0 + CT, len);   // valid (masked-in) end

    const float4* __restrict__ xp = (const float4*)(x + (size_t)b * TT * DD);
    float4* __restrict__ op = (float4*)(out + (size_t)b * TT * DD);

    float4 pre = ((const float4*)ws)[((size_t)b * NC + c) * D4 + d4];

    int t = t0;
    #pragma unroll 4
    for (; t < tv; ++t) {
        float4 v = xp[(size_t)t * D4 + d4];
        pre.x += gelu_exact(v.x);
        pre.y += gelu_exact(v.y);
        pre.z += gelu_exact(v.z);
        pre.w += gelu_exact(v.w);
        float4 o;
        o.x = v.x + pre.x;
        o.y = v.y + pre.y;
        o.z = v.z + pre.z;
        o.w = v.w + pre.w;
        op[(size_t)t * D4 + d4] = o;
    }
    // rows at/after length: plain copy (mask is 0)
    #pragma unroll 4
    for (; t < t0 + CT; ++t) {
        op[(size_t)t * D4 + d4] = xp[(size_t)t * D4 + d4];
    }
}

extern "C" void kernel_launch(void* const* d_in, const int* in_sizes, int n_in,
                              void* d_out, int out_size, void* d_ws, size_t ws_size,
                              hipStream_t stream) {
    const float* x       = (const float*)d_in[0];
    const int*   lengths = (const int*)d_in[1];
    float*       out     = (float*)d_out;
    float*       ws      = (float*)d_ws;   // needs B*NC*D*4 = 8 MB

    dim3 blk(256, 1, 1);
    dim3 g1(NC, BB, 1);
    hipLaunchKernelGGL(k_partial, g1, blk, 0, stream, x, lengths, ws);

    dim3 g2(BB * DD / 4, 1, 1);
    hipLaunchKernelGGL(k_scan, g2, blk, 0, stream, ws);

    hipLaunchKernelGGL(k_apply, g1, blk, 0, stream, x, lengths, ws, out);
}

// Round 4
// 269.023 us; speedup vs baseline: 1.1165x; 1.0670x over previous
//
#include <hip/hip_runtime.h>
#include <math.h>

// Problem constants (from reference: B=8, T=4096, D=1024, fp32)
#define BB 8
#define TT 4096
#define DD 1024
#define NC 256           // number of T-chunks
#define CT (TT / NC)     // chunk length = 16
#define D4 (DD / 4)      // float4s per row = 256

// native clang vector type — accepted by __builtin_nontemporal_store
typedef float vfloat4 __attribute__((ext_vector_type(4)));

__device__ __forceinline__ float gelu_exact(float v) {
    // exact GELU: 0.5*v*(1+erf(v/sqrt(2)))
    return 0.5f * v * (1.0f + erff(v * 0.70710678118654752f));
}

// Pass 1: per-(b,chunk) masked sums of gelu(x) over the chunk's T range.
// ws layout: [B][NC][D] floats (8 MB).
__global__ __launch_bounds__(256)
void k_partial(const float* __restrict__ x, const int* __restrict__ lengths,
               float* __restrict__ ws) {
    const int c  = blockIdx.x;       // chunk
    const int b  = blockIdx.y;       // batch
    const int d4 = threadIdx.x;      // 0..255 (float4 column)
    const int len = lengths[b];
    const int t0 = c * CT;
    const int t1 = min(t0 + CT, len);   // masked end (g==0 beyond len)

    const float4* __restrict__ xp = (const float4*)(x + (size_t)b * TT * DD);
    float4 s = make_float4(0.f, 0.f, 0.f, 0.f);
    #pragma unroll 4
    for (int t = t0; t < t1; ++t) {
        float4 v = xp[(size_t)t * D4 + d4];
        s.x += gelu_exact(v.x);
        s.y += gelu_exact(v.y);
        s.z += gelu_exact(v.z);
        s.w += gelu_exact(v.w);
    }
    ((float4*)ws)[((size_t)b * NC + c) * D4 + d4] = s;
}

// Pass 2: in-place exclusive scan along NC. One block per (b, 256-wide d-tile):
// 32 blocks, each thread owns one d column (running sum in a register),
// serial over c with fully COALESCED 1 KB loads/stores. Unrolled so the
// compiler keeps ~8 independent loads in flight (addresses provably disjoint:
// consecutive c offsets differ by DD*4 bytes).
__global__ __launch_bounds__(256)
void k_scan(float* __restrict__ ws) {
    const int b     = blockIdx.x >> 2;             // / 4
    const int dtile = blockIdx.x & 3;              // % 4
    const int d     = dtile * 256 + threadIdx.x;   // 0..1023
    float* p = ws + (size_t)b * NC * DD + d;
    float run = 0.f;
    #pragma unroll 8
    for (int c = 0; c < NC; ++c) {
        float v = p[(size_t)c * DD];
        p[(size_t)c * DD] = run;
        run += v;
    }
}

// Pass 3: re-read x (L3-warm), add exclusive chunk offset + local running
// prefix. Output stores are nontemporal so the 134 MB stream doesn't evict x.
__global__ __launch_bounds__(256)
void k_apply(const float* __restrict__ x, const int* __restrict__ lengths,
             const float* __restrict__ ws, float* __restrict__ out) {
    const int c  = blockIdx.x;
    const int b  = blockIdx.y;
    const int d4 = threadIdx.x;
    const int len = lengths[b];
    const int t0 = c * CT;
    const int tv = min(t0 + CT, len);   // valid (masked-in) end

    const float4* __restrict__ xp = (const float4*)(x + (size_t)b * TT * DD);
    vfloat4* __restrict__ op = (vfloat4*)(out + (size_t)b * TT * DD);

    float4 pre = ((const float4*)ws)[((size_t)b * NC + c) * D4 + d4];

    int t = t0;
    #pragma unroll 4
    for (; t < tv; ++t) {
        float4 v = xp[(size_t)t * D4 + d4];
        pre.x += gelu_exact(v.x);
        pre.y += gelu_exact(v.y);
        pre.z += gelu_exact(v.z);
        pre.w += gelu_exact(v.w);
        vfloat4 o = {v.x + pre.x, v.y + pre.y, v.z + pre.z, v.w + pre.w};
        __builtin_nontemporal_store(o, &op[(size_t)t * D4 + d4]);
    }
    // rows at/after length: plain copy (mask is 0)
    #pragma unroll 4
    for (; t < t0 + CT; ++t) {
        float4 v = xp[(size_t)t * D4 + d4];
        vfloat4 o = {v.x, v.y, v.z, v.w};
        __builtin_nontemporal_store(o, &op[(size_t)t * D4 + d4]);
    }
}

extern "C" void kernel_launch(void* const* d_in, const int* in_sizes, int n_in,
                              void* d_out, int out_size, void* d_ws, size_t ws_size,
                              hipStream_t stream) {
    const float* x       = (const float*)d_in[0];
    const int*   lengths = (const int*)d_in[1];
    float*       out     = (float*)d_out;
    float*       ws      = (float*)d_ws;   // needs B*NC*D*4 = 8 MB

    dim3 blk(256, 1, 1);
    dim3 g1(NC, BB, 1);
    hipLaunchKernelGGL(k_partial, g1, blk, 0, stream, x, lengths, ws);

    dim3 g2(BB * 4, 1, 1);   // 32 blocks: (b, 256-wide d-tile)
    hipLaunchKernelGGL(k_scan, g2, blk, 0, stream, ws);

    hipLaunchKernelGGL(k_apply, g1, blk, 0, stream, x, lengths, ws, out);
}